// Round 1
// baseline (882.875 us; speedup 1.0000x reference)
//
#include <hip/hip_runtime.h>
#include <stdint.h>

#define BB 64
#define SS 256
#define DD 1024
#define BETA_C 0.75f
#define INV_TEMP 10.0f

typedef float f32x4 __attribute__((ext_vector_type(4)));
typedef short bf16x8 __attribute__((ext_vector_type(8)));

__device__ __forceinline__ unsigned short f2bf(float f) {
  union { float f; unsigned int u; } v; v.f = f;
  unsigned int u = v.u;
  unsigned int r = (u + 0x7fffu + ((u >> 16) & 1u)) >> 16;
  return (unsigned short)r;
}

// ---- W -> bf16 ----
__global__ __launch_bounds__(256) void kconv_w(const float* __restrict__ W,
                                               ushort* __restrict__ Wb) {
  int idx = blockIdx.x * 256 + threadIdx.x;  // each handles 4 floats
  float4 v = ((const float4*)W)[idx];
  ushort4 o;
  o.x = f2bf(v.x); o.y = f2bf(v.y); o.z = f2bf(v.z); o.w = f2bf(v.w);
  ((ushort4*)Wb)[idx] = o;
}

// ---- per-b: i, iCi = i@C_inv, inv_ie, co = i@W^T ----
__global__ __launch_bounds__(256) void k1(
    const int* __restrict__ pid, const float* __restrict__ text,
    const int* __restrict__ cidx, const float* __restrict__ W,
    const float* __restrict__ Cinv, const unsigned char* __restrict__ initted,
    const float* __restrict__ ema,
    float* __restrict__ iCi, float* __restrict__ inv_ie, float* __restrict__ co) {
  __shared__ float i_sm[DD];
  __shared__ float red[4];
  int b = blockIdx.x, t = threadIdx.x;
  int p = pid[b];
  bool flag = initted[p] != 0;
  const float* src = flag ? (ema + (size_t)p * DD)
                          : (text + ((size_t)b * SS + cidx[b]) * DD);
  float4 iv = ((const float4*)src)[t];
  ((float4*)i_sm)[t] = iv;
  __syncthreads();

  // iCi[d], d = 4t..4t+3 : coalesced over C_inv rows
  float ax = 0.f, ay = 0.f, az = 0.f, aw = 0.f;
  for (int k = 0; k < DD; ++k) {
    float ik = i_sm[k];
    float4 c = ((const float4*)(Cinv + (size_t)k * DD))[t];
    ax += ik * c.x; ay += ik * c.y; az += ik * c.z; aw += ik * c.w;
  }
  float4 accv; accv.x = ax; accv.y = ay; accv.z = az; accv.w = aw;
  ((float4*)(iCi + (size_t)b * DD))[t] = accv;

  float part = ax * iv.x + ay * iv.y + az * iv.z + aw * iv.w;
#pragma unroll
  for (int off = 32; off; off >>= 1) part += __shfl_down(part, off, 64);
  if ((t & 63) == 0) red[t >> 6] = part;
  __syncthreads();
  if (t == 0) {
    float ie = red[0] + red[1] + red[2] + red[3];
    inv_ie[b] = 1.0f / ie;
  }

  // co[o] = sum_i i[i] * W[o,i]; wave w handles o = w*256 + idx
  int w = t >> 6, lane = t & 63;
  const float4* ism4 = (const float4*)i_sm;
  float4 i0 = ism4[lane], i1 = ism4[lane + 64], i2 = ism4[lane + 128], i3 = ism4[lane + 192];
  for (int idx = 0; idx < 256; ++idx) {
    int o = w * 256 + idx;
    const float4* wr = (const float4*)(W + (size_t)o * DD);
    float4 a0 = wr[lane], a1 = wr[lane + 64], a2 = wr[lane + 128], a3 = wr[lane + 192];
    float s = a0.x * i0.x + a0.y * i0.y + a0.z * i0.z + a0.w * i0.w
            + a1.x * i1.x + a1.y * i1.y + a1.z * i1.z + a1.w * i1.w
            + a2.x * i2.x + a2.y * i2.y + a2.z * i2.z + a2.w * i2.w
            + a3.x * i3.x + a3.y * i3.y + a3.z * i3.z + a3.w * i3.w;
#pragma unroll
    for (int off = 32; off; off >>= 1) s += __shfl_down(s, off, 64);
    if (lane == 0) co[(size_t)b * DD + o] = s;
  }
}

// ---- sim + sigmoid + text->bf16 (one wave per row) ----
__global__ __launch_bounds__(256) void k_sim(
    const float* __restrict__ text, const float* __restrict__ iCi,
    const float* __restrict__ inv_ie,
    ushort* __restrict__ textb, float* __restrict__ s1, float* __restrict__ s2) {
  int row = blockIdx.x * 4 + (threadIdx.x >> 6);  // 0..16383
  int lane = threadIdx.x & 63;
  int b = row >> 8;
  const float4* tr = (const float4*)(text + (size_t)row * DD);
  const float4* cr = (const float4*)(iCi + (size_t)b * DD);
  ushort4* ob = ((ushort4*)textb) + (size_t)row * (DD / 4);
  float part = 0.f;
#pragma unroll
  for (int j = 0; j < 4; ++j) {
    int idx = lane + 64 * j;
    float4 t4 = tr[idx], c4 = cr[idx];
    part += t4.x * c4.x + t4.y * c4.y + t4.z * c4.z + t4.w * c4.w;
    ushort4 u;
    u.x = f2bf(t4.x); u.y = f2bf(t4.y); u.z = f2bf(t4.z); u.w = f2bf(t4.w);
    ob[idx] = u;
  }
#pragma unroll
  for (int off = 32; off; off >>= 1) part += __shfl_down(part, off, 64);
  if (lane == 0) {
    float v = part * inv_ie[b];
    s1[row] = v;
    s2[row] = 1.0f / (1.0f + expf(-(v - BETA_C) * INV_TEMP));
  }
}

// ---- main GEMM (bf16 MFMA, 128x128 tile, BK=32) + fused epilogue ----
__global__ __launch_bounds__(256) void k2(
    const ushort* __restrict__ Ab, const ushort* __restrict__ Bb,
    const float* __restrict__ s1, const float* __restrict__ s2,
    const float* __restrict__ co,
    const int* __restrict__ pid, const unsigned char* __restrict__ initted,
    const float* __restrict__ otabf,
    float* __restrict__ out) {
  __shared__ ushort As[128 * 32];
  __shared__ ushort Bs[128 * 32];
  int tileN = blockIdx.x;  // 0..7
  int tileM = blockIdx.y;  // 0..127
  int t = threadIdx.x;
  int w = t >> 6, lane = t & 63;
  int wm = w >> 1, wn = w & 1;
  int b = tileM >> 1;  // 128-row tiles: 2 per batch element

  int lrow = lane >> 2;        // 0..15
  int lk = (lane & 3) * 8;     // bf16 col offset 0/8/16/24

  f32x4 acc[4][4];
#pragma unroll
  for (int mf = 0; mf < 4; ++mf)
#pragma unroll
    for (int nf = 0; nf < 4; ++nf) {
      f32x4 z = {0.f, 0.f, 0.f, 0.f};
      acc[mf][nf] = z;
    }

  for (int kt = 0; kt < 32; ++kt) {
    __syncthreads();  // previous compute done before overwrite
#pragma unroll
    for (int r = 0; r < 2; ++r) {
      int row = w * 16 + r * 64 + lrow;
      const ushort* ga = Ab + (size_t)(tileM * 128 + row) * DD + kt * 32 + lk;
      __builtin_amdgcn_global_load_lds(
          (const __attribute__((address_space(1))) uint32_t*)ga,
          (__attribute__((address_space(3))) uint32_t*)(As + w * 512 + r * 2048),
          16, 0, 0);
      const ushort* gb = Bb + (size_t)(tileN * 128 + row) * DD + kt * 32 + lk;
      __builtin_amdgcn_global_load_lds(
          (const __attribute__((address_space(1))) uint32_t*)gb,
          (__attribute__((address_space(3))) uint32_t*)(Bs + w * 512 + r * 2048),
          16, 0, 0);
    }
    __syncthreads();  // drains vmcnt before barrier

    bf16x8 af[4], bfr[4];
#pragma unroll
    for (int mf = 0; mf < 4; ++mf)
      af[mf] = *(const bf16x8*)(As + (wm * 64 + mf * 16 + (lane & 15)) * 32 + (lane >> 4) * 8);
#pragma unroll
    for (int nf = 0; nf < 4; ++nf)
      bfr[nf] = *(const bf16x8*)(Bs + (wn * 64 + nf * 16 + (lane & 15)) * 32 + (lane >> 4) * 8);
#pragma unroll
    for (int mf = 0; mf < 4; ++mf)
#pragma unroll
      for (int nf = 0; nf < 4; ++nf)
        acc[mf][nf] = __builtin_amdgcn_mfma_f32_16x16x32_bf16(af[mf], bfr[nf], acc[mf][nf], 0, 0, 0);
  }

  // epilogue: out = orig - s1*co + s2*outs   (outs = orig when !initted)
  int p = pid[b];
  bool flag = initted[p] != 0;
  int colbase = tileN * 128 + wn * 64;
  int rowbase = tileM * 128 + wm * 64;
  float cov[4];
#pragma unroll
  for (int nf = 0; nf < 4; ++nf)
    cov[nf] = co[(size_t)b * DD + colbase + nf * 16 + (lane & 15)];

  if (!flag) {
#pragma unroll
    for (int mf = 0; mf < 4; ++mf) {
#pragma unroll
      for (int reg = 0; reg < 4; ++reg) {
        int rowg = rowbase + mf * 16 + (lane >> 4) * 4 + reg;
        float a = s1[rowg], g = 1.0f + s2[rowg];
#pragma unroll
        for (int nf = 0; nf < 4; ++nf) {
          int col = colbase + nf * 16 + (lane & 15);
          float orig = acc[mf][nf][reg];
          out[(size_t)rowg * DD + col] = orig * g - a * cov[nf];
        }
      }
    }
  } else {
    const float* otab = otabf + (size_t)p * SS * DD;
#pragma unroll
    for (int mf = 0; mf < 4; ++mf) {
#pragma unroll
      for (int reg = 0; reg < 4; ++reg) {
        int rowg = rowbase + mf * 16 + (lane >> 4) * 4 + reg;
        float a = s1[rowg], g = s2[rowg];
        int n = rowg & 255;
#pragma unroll
        for (int nf = 0; nf < 4; ++nf) {
          int col = colbase + nf * 16 + (lane & 15);
          float orig = acc[mf][nf][reg];
          float outs = otab[(size_t)n * DD + col];
          out[(size_t)rowg * DD + col] = orig - a * cov[nf] + g * outs;
        }
      }
    }
  }
}

extern "C" void kernel_launch(void* const* d_in, const int* in_sizes, int n_in,
                              void* d_out, int out_size, void* d_ws, size_t ws_size,
                              hipStream_t stream) {
  const int* pid = (const int*)d_in[0];
  const float* text = (const float*)d_in[1];
  const int* cidx = (const int*)d_in[2];
  const float* W = (const float*)d_in[3];
  const float* Cinv = (const float*)d_in[4];
  const unsigned char* initted = (const unsigned char*)d_in[5];
  const float* ema = (const float*)d_in[6];
  const float* otab = (const float*)d_in[7];
  float* out = (float*)d_out;

  char* ws = (char*)d_ws;
  ushort* textb = (ushort*)ws;                          // 33,554,432 B
  ushort* Wb = (ushort*)(ws + 33554432);                // 2,097,152 B
  float* iCi = (float*)(ws + 35651584);                 // 262,144 B
  float* co_ = (float*)(ws + 35913728);                 // 262,144 B
  float* iie = (float*)(ws + 36175872);                 // 256 B
  float* s1 = (float*)(ws + 36176128);                  // 65,536 B
  float* s2 = (float*)(ws + 36241664);                  // 65,536 B

  hipLaunchKernelGGL(kconv_w, dim3(1024), dim3(256), 0, stream, W, Wb);
  hipLaunchKernelGGL(k1, dim3(64), dim3(256), 0, stream,
                     pid, text, cidx, W, Cinv, initted, ema, iCi, iie, co_);
  hipLaunchKernelGGL(k_sim, dim3(4096), dim3(256), 0, stream,
                     text, iCi, iie, textb, s1, s2);
  hipLaunchKernelGGL(k2, dim3(8, 128), dim3(256), 0, stream,
                     textb, Wb, s1, s2, co_, pid, initted, otab, out);
}

// Round 2
// 704.581 us; speedup vs baseline: 1.2530x; 1.2530x over previous
//
#include <hip/hip_runtime.h>
#include <stdint.h>

#define BB 64
#define SS 256
#define DD 1024
#define BETA_C 0.75f
#define INV_TEMP 10.0f

typedef float f32x4 __attribute__((ext_vector_type(4)));
typedef short bf16x8 __attribute__((ext_vector_type(8)));

__device__ __forceinline__ unsigned short f2bf(float f) {
  union { float f; unsigned int u; } v; v.f = f;
  unsigned int u = v.u;
  unsigned int r = (u + 0x7fffu + ((u >> 16) & 1u)) >> 16;
  return (unsigned short)r;
}

// ---- prep: W->bf16 (blocks 0..1023), Cinv->bf16 (1024..2047), gather I (2048..2111) ----
__global__ __launch_bounds__(256) void kprep(
    const float* __restrict__ W, const float* __restrict__ Cinv,
    const int* __restrict__ pid, const float* __restrict__ text,
    const int* __restrict__ cidx, const unsigned char* __restrict__ initted,
    const float* __restrict__ ema,
    ushort* __restrict__ Wb, ushort* __restrict__ Cb,
    ushort* __restrict__ Ib, float* __restrict__ If) {
  int bid = blockIdx.x, t = threadIdx.x;
  if (bid < 2048) {
    const float* src = (bid < 1024) ? W : Cinv;
    ushort* dst = (bid < 1024) ? Wb : Cb;
    int idx = (bid & 1023) * 256 + t;
    float4 v = ((const float4*)src)[idx];
    ushort4 o;
    o.x = f2bf(v.x); o.y = f2bf(v.y); o.z = f2bf(v.z); o.w = f2bf(v.w);
    ((ushort4*)dst)[idx] = o;
  } else {
    int b = bid - 2048;
    int p = pid[b];
    bool flag = initted[p] != 0;
    const float* src = flag ? (ema + (size_t)p * DD)
                            : (text + ((size_t)b * SS + cidx[b]) * DD);
    float4 v = ((const float4*)src)[t];
    ((float4*)(If + (size_t)b * DD))[t] = v;
    ushort4 o;
    o.x = f2bf(v.x); o.y = f2bf(v.y); o.z = f2bf(v.z); o.w = f2bf(v.w);
    ((ushort4*)(Ib + (size_t)b * DD))[t] = o;
  }
}

// ---- small GEMM: [64x1024] = I @ {Cinv, W}^T  (both row-major, Cinv symmetric) ----
// grid (8, 2): x = 128-col block, y = 0:Cinv->iCi(+ie partials), 1:W->co
__global__ __launch_bounds__(256) void kgemm64(
    const ushort* __restrict__ Ib, const ushort* __restrict__ Cb,
    const ushort* __restrict__ Wb, const float* __restrict__ If,
    float* __restrict__ iCi, float* __restrict__ co,
    float* __restrict__ ie_part) {
  __shared__ ushort As[64 * 32];
  __shared__ ushort Bs[128 * 32];
  int nb = blockIdx.x;
  int z = blockIdx.y;
  const ushort* Bsrc = z ? Wb : Cb;
  int t = threadIdx.x;
  int w = t >> 6, lane = t & 63;

  f32x4 acc[4][2];
#pragma unroll
  for (int mf = 0; mf < 4; ++mf)
#pragma unroll
    for (int j = 0; j < 2; ++j) {
      f32x4 zz = {0.f, 0.f, 0.f, 0.f};
      acc[mf][j] = zz;
    }

  for (int kt = 0; kt < 32; ++kt) {
    __syncthreads();
    {
      int row = t >> 2, ck = (t & 3) * 8;
      const ushort* ga = Ib + (size_t)row * DD + kt * 32 + ck;
      __builtin_amdgcn_global_load_lds(
          (const __attribute__((address_space(1))) uint32_t*)ga,
          (__attribute__((address_space(3))) uint32_t*)(As + (w * 64 + lane) * 8),
          16, 0, 0);
    }
#pragma unroll
    for (int r = 0; r < 2; ++r) {
      int row = r * 64 + (t >> 2);
      const ushort* gb = Bsrc + (size_t)(nb * 128 + row) * DD + kt * 32 + (t & 3) * 8;
      __builtin_amdgcn_global_load_lds(
          (const __attribute__((address_space(1))) uint32_t*)gb,
          (__attribute__((address_space(3))) uint32_t*)(Bs + r * 2048 + (w * 64 + lane) * 8),
          16, 0, 0);
    }
    __syncthreads();

    bf16x8 af[4], bfr[2];
#pragma unroll
    for (int mf = 0; mf < 4; ++mf)
      af[mf] = *(const bf16x8*)(As + (mf * 16 + (lane & 15)) * 32 + (lane >> 4) * 8);
#pragma unroll
    for (int j = 0; j < 2; ++j)
      bfr[j] = *(const bf16x8*)(Bs + ((w * 2 + j) * 16 + (lane & 15)) * 32 + (lane >> 4) * 8);
#pragma unroll
    for (int mf = 0; mf < 4; ++mf)
#pragma unroll
      for (int j = 0; j < 2; ++j)
        acc[mf][j] = __builtin_amdgcn_mfma_f32_16x16x32_bf16(af[mf], bfr[j], acc[mf][j], 0, 0, 0);
  }

  int colb = nb * 128 + w * 32;
  float* outp = z ? co : iCi;
#pragma unroll
  for (int mf = 0; mf < 4; ++mf)
#pragma unroll
    for (int reg = 0; reg < 4; ++reg) {
      int row = mf * 16 + (lane >> 4) * 4 + reg;
#pragma unroll
      for (int j = 0; j < 2; ++j) {
        int col = colb + j * 16 + (lane & 15);
        outp[(size_t)row * DD + col] = acc[mf][j][reg];
      }
    }

  if (!z) {
    // i_energy partials: per (row, block, wave) over this wave's 32 cols
#pragma unroll
    for (int mf = 0; mf < 4; ++mf)
#pragma unroll
      for (int reg = 0; reg < 4; ++reg) {
        int row = mf * 16 + (lane >> 4) * 4 + reg;
        float s = 0.f;
#pragma unroll
        for (int j = 0; j < 2; ++j) {
          int col = colb + j * 16 + (lane & 15);
          s += acc[mf][j][reg] * If[(size_t)row * DD + col];
        }
        s += __shfl_xor(s, 1);
        s += __shfl_xor(s, 2);
        s += __shfl_xor(s, 4);
        s += __shfl_xor(s, 8);
        if ((lane & 15) == 0)
          ie_part[(size_t)row * 32 + nb * 4 + w] = s;
      }
  }
}

// ---- sim + sigmoid + text->bf16 (one wave per row) ----
__global__ __launch_bounds__(256) void k_sim(
    const float* __restrict__ text, const float* __restrict__ iCi,
    const float* __restrict__ ie_part,
    ushort* __restrict__ textb, float* __restrict__ s1, float* __restrict__ s2) {
  int row = blockIdx.x * 4 + (threadIdx.x >> 6);
  int lane = threadIdx.x & 63;
  int b = row >> 8;
  const float4* tr = (const float4*)(text + (size_t)row * DD);
  const float4* cr = (const float4*)(iCi + (size_t)b * DD);
  ushort4* ob = ((ushort4*)textb) + (size_t)row * (DD / 4);
  float part = 0.f;
#pragma unroll
  for (int j = 0; j < 4; ++j) {
    int idx = lane + 64 * j;
    float4 t4 = tr[idx], c4 = cr[idx];
    part += t4.x * c4.x + t4.y * c4.y + t4.z * c4.z + t4.w * c4.w;
    ushort4 u;
    u.x = f2bf(t4.x); u.y = f2bf(t4.y); u.z = f2bf(t4.z); u.w = f2bf(t4.w);
    ob[idx] = u;
  }
#pragma unroll
  for (int off = 32; off; off >>= 1) part += __shfl_down(part, off, 64);
  if (lane == 0) {
    float ie = 0.f;
#pragma unroll
    for (int q = 0; q < 32; ++q) ie += ie_part[(size_t)b * 32 + q];
    float v = part / ie;
    s1[row] = v;
    s2[row] = 1.0f / (1.0f + expf(-(v - BETA_C) * INV_TEMP));
  }
}

// ---- main GEMM (bf16 MFMA, 128x128 tile, BK=32) + fused epilogue ----
__global__ __launch_bounds__(256) void k2(
    const ushort* __restrict__ Ab, const ushort* __restrict__ Bb,
    const float* __restrict__ s1, const float* __restrict__ s2,
    const float* __restrict__ co,
    const int* __restrict__ pid, const unsigned char* __restrict__ initted,
    const float* __restrict__ otabf,
    float* __restrict__ out) {
  __shared__ ushort As[128 * 32];
  __shared__ ushort Bs[128 * 32];
  // XCD-chunked bijective swizzle: each XCD gets contiguous tileM range x all tileN
  int id = blockIdx.y * 8 + blockIdx.x;       // 0..1023, x-fastest = dispatch order
  int sw = (id & 7) * 128 + (id >> 3);
  int tileM = sw >> 3;                         // 0..127
  int tileN = sw & 7;                          // 0..7
  int t = threadIdx.x;
  int w = t >> 6, lane = t & 63;
  int wm = w >> 1, wn = w & 1;
  int b = tileM >> 1;

  int lrow = lane >> 2;
  int lk = (lane & 3) * 8;

  f32x4 acc[4][4];
#pragma unroll
  for (int mf = 0; mf < 4; ++mf)
#pragma unroll
    for (int nf = 0; nf < 4; ++nf) {
      f32x4 z = {0.f, 0.f, 0.f, 0.f};
      acc[mf][nf] = z;
    }

  for (int kt = 0; kt < 32; ++kt) {
    __syncthreads();
#pragma unroll
    for (int r = 0; r < 2; ++r) {
      int row = w * 16 + r * 64 + lrow;
      const ushort* ga = Ab + (size_t)(tileM * 128 + row) * DD + kt * 32 + lk;
      __builtin_amdgcn_global_load_lds(
          (const __attribute__((address_space(1))) uint32_t*)ga,
          (__attribute__((address_space(3))) uint32_t*)(As + w * 512 + r * 2048),
          16, 0, 0);
      const ushort* gb = Bb + (size_t)(tileN * 128 + row) * DD + kt * 32 + lk;
      __builtin_amdgcn_global_load_lds(
          (const __attribute__((address_space(1))) uint32_t*)gb,
          (__attribute__((address_space(3))) uint32_t*)(Bs + w * 512 + r * 2048),
          16, 0, 0);
    }
    __syncthreads();

    bf16x8 af[4], bfr[4];
#pragma unroll
    for (int mf = 0; mf < 4; ++mf)
      af[mf] = *(const bf16x8*)(As + (wm * 64 + mf * 16 + (lane & 15)) * 32 + (lane >> 4) * 8);
#pragma unroll
    for (int nf = 0; nf < 4; ++nf)
      bfr[nf] = *(const bf16x8*)(Bs + (wn * 64 + nf * 16 + (lane & 15)) * 32 + (lane >> 4) * 8);
#pragma unroll
    for (int mf = 0; mf < 4; ++mf)
#pragma unroll
      for (int nf = 0; nf < 4; ++nf)
        acc[mf][nf] = __builtin_amdgcn_mfma_f32_16x16x32_bf16(af[mf], bfr[nf], acc[mf][nf], 0, 0, 0);
  }

  int p = pid[b];
  bool flag = initted[p] != 0;
  int colbase = tileN * 128 + wn * 64;
  int rowbase = tileM * 128 + wm * 64;
  float cov[4];
#pragma unroll
  for (int nf = 0; nf < 4; ++nf)
    cov[nf] = co[(size_t)b * DD + colbase + nf * 16 + (lane & 15)];

  if (!flag) {
#pragma unroll
    for (int mf = 0; mf < 4; ++mf) {
#pragma unroll
      for (int reg = 0; reg < 4; ++reg) {
        int rowg = rowbase + mf * 16 + (lane >> 4) * 4 + reg;
        float a = s1[rowg], g = 1.0f + s2[rowg];
#pragma unroll
        for (int nf = 0; nf < 4; ++nf) {
          int col = colbase + nf * 16 + (lane & 15);
          float orig = acc[mf][nf][reg];
          out[(size_t)rowg * DD + col] = orig * g - a * cov[nf];
        }
      }
    }
  } else {
    const float* otab = otabf + (size_t)p * SS * DD;
#pragma unroll
    for (int mf = 0; mf < 4; ++mf) {
#pragma unroll
      for (int reg = 0; reg < 4; ++reg) {
        int rowg = rowbase + mf * 16 + (lane >> 4) * 4 + reg;
        float a = s1[rowg], g = s2[rowg];
        int n = rowg & 255;
#pragma unroll
        for (int nf = 0; nf < 4; ++nf) {
          int col = colbase + nf * 16 + (lane & 15);
          float orig = acc[mf][nf][reg];
          float outs = otab[(size_t)n * DD + col];
          out[(size_t)rowg * DD + col] = orig - a * cov[nf] + g * outs;
        }
      }
    }
  }
}

extern "C" void kernel_launch(void* const* d_in, const int* in_sizes, int n_in,
                              void* d_out, int out_size, void* d_ws, size_t ws_size,
                              hipStream_t stream) {
  const int* pid = (const int*)d_in[0];
  const float* text = (const float*)d_in[1];
  const int* cidx = (const int*)d_in[2];
  const float* W = (const float*)d_in[3];
  const float* Cinv = (const float*)d_in[4];
  const unsigned char* initted = (const unsigned char*)d_in[5];
  const float* ema = (const float*)d_in[6];
  const float* otab = (const float*)d_in[7];
  float* out = (float*)d_out;

  char* ws = (char*)d_ws;
  ushort* textb = (ushort*)ws;                      // 33,554,432 B
  ushort* Wb = (ushort*)(ws + 33554432);            // 2,097,152 B
  ushort* Cb = (ushort*)(ws + 35651584);            // 2,097,152 B
  ushort* Ib = (ushort*)(ws + 37748736);            // 131,072 B
  float* If = (float*)(ws + 37879808);              // 262,144 B
  float* iCi = (float*)(ws + 38141952);             // 262,144 B
  float* co_ = (float*)(ws + 38404096);             // 262,144 B
  float* iep = (float*)(ws + 38666240);             // 8,192 B
  float* s1 = (float*)(ws + 38674432);              // 65,536 B
  float* s2 = (float*)(ws + 38739968);              // 65,536 B

  hipLaunchKernelGGL(kprep, dim3(2112), dim3(256), 0, stream,
                     W, Cinv, pid, text, cidx, initted, ema, Wb, Cb, Ib, If);
  hipLaunchKernelGGL(kgemm64, dim3(8, 2), dim3(256), 0, stream,
                     Ib, Cb, Wb, If, iCi, co_, iep);
  hipLaunchKernelGGL(k_sim, dim3(4096), dim3(256), 0, stream,
                     text, iCi, iep, textb, s1, s2);
  hipLaunchKernelGGL(k2, dim3(8, 128), dim3(256), 0, stream,
                     textb, Wb, s1, s2, co_, pid, initted, otab, out);
}